// Round 1
// baseline (655.109 us; speedup 1.0000x reference)
//
#include <hip/hip_runtime.h>
#include <hip/hip_bf16.h>
#include <stdint.h>

// Batched tiny MLP: [B,13] -> 16 -> (30x 16->16 relu) -> 1, fp32 in/out.
// Strategy: transposed formulation h^T = relu(W h^T + b) so that the
// mfma_f32_16x16x16_bf16 D layout (row=(lane>>4)*4+reg, col=lane&15) equals
// the B-operand layout (k=(lane>>4)*4+i, n=lane&15): each layer's output is
// the next layer's B fragment with no cross-lane movement. Bias rides in the
// MFMA C operand. fp32 accumulate throughout; only A/B inputs are bf16.

typedef __attribute__((ext_vector_type(4))) short short4v;
typedef __attribute__((ext_vector_type(4))) float float4v;

#define S_IN 13
#define H 16
#define NL 32          // mfma layers: 0 = input, 1..30 = hidden, 31 = output
#define TPB 256
#define WPB 4          // waves per block
#define T 4            // 16-sample tiles per wave

__device__ __forceinline__ unsigned short bf16_rne(float x) {
    unsigned u = __float_as_uint(x);
    u += 0x7fffu + ((u >> 16) & 1u);
    return (unsigned short)(u >> 16);
}

__device__ __forceinline__ int pk_bf16(float a, float b) {
#if __has_builtin(__builtin_amdgcn_cvt_pk_bf16_f32)
    typedef __attribute__((ext_vector_type(2))) __bf16 bf16x2;
    bf16x2 v = __builtin_amdgcn_cvt_pk_bf16_f32(a, b);
    return __builtin_bit_cast(int, v);
#else
    return (int)bf16_rne(a) | ((int)bf16_rne(b) << 16);
#endif
}

// Pre-swizzle weights into MFMA A-fragment layout (bf16) and biases into
// C-operand order (fp32) in the workspace. ws layout:
//   [0, 16384)      short4v A[32][64]   (lane l holds A[m=l&15][k=4*(l>>4)+i])
//   [16384, 18432)  float   bias[32][16]
__global__ void prep_kernel(const float* __restrict__ W_in, const float* __restrict__ b_in,
                            const float* __restrict__ W_h,  const float* __restrict__ b_h,
                            const float* __restrict__ W_out,const float* __restrict__ b_out,
                            short4v* __restrict__ wsA, float* __restrict__ wsB) {
    const int L = blockIdx.x;          // 0..31
    const int lane = threadIdx.x;      // 0..63
    const int m = lane & 15;
    const int g = lane >> 4;
    short4v s;
#pragma unroll
    for (int i = 0; i < 4; ++i) {
        const int k = 4 * g + i;
        float v;
        if (L == 0)         v = (k < S_IN) ? W_in[m * S_IN + k] : 0.f;
        else if (L <= 30)   v = W_h[(L - 1) * H * H + m * H + k];
        else                v = (m == 0) ? W_out[k] : 0.f;
        s[i] = (short)bf16_rne(v);
    }
    wsA[L * 64 + lane] = s;
    if (lane < 16) {
        float bv;
        if (L == 0)         bv = b_in[m];
        else if (L <= 30)   bv = b_h[(L - 1) * H + m];
        else                bv = (m == 0) ? b_out[0] : 0.f;
        wsB[L * H + m] = bv;
    }
}

__global__ __launch_bounds__(TPB, 6)
void mlp_kernel(const float* __restrict__ x, float* __restrict__ out,
                const float4v* __restrict__ ws, int tiles) {
    // 18 KB: [0,1024) float4 = A-frags (as short4 pairs), [1024,1152) = biases
    __shared__ float4v smem[1152];
    for (int i = threadIdx.x; i < 1152; i += TPB) smem[i] = ws[i];
    __syncthreads();

    const short4v* lA = (const short4v*)smem;
    const float4v* lB = smem + 1024;

    const int lane = threadIdx.x & 63;
    const int wv   = threadIdx.x >> 6;
    const int g    = lane >> 4;        // k/m group (0..3)
    const int col  = lane & 15;        // sample within tile
    const int k0   = 4 * g;

    const int wave_id = blockIdx.x * WPB + wv;
    const int stride  = gridDim.x * WPB * T;

    for (int tb = wave_id * T; tb < tiles; tb += stride) {
        // ---- build input-layer B fragments: B[k][n] = x[n][k], k padded to 16
        short4v bf[T];
#pragma unroll
        for (int t = 0; t < T; ++t) {
            const int n = (tb + t) * 16 + col;
            const float* xp = x + (size_t)n * S_IN + k0;
            float v0 = (k0 + 0 < S_IN) ? xp[0] : 0.f;
            float v1 = (k0 + 1 < S_IN) ? xp[1] : 0.f;
            float v2 = (k0 + 2 < S_IN) ? xp[2] : 0.f;
            float v3 = (k0 + 3 < S_IN) ? xp[3] : 0.f;
            int2 p;
            p.x = pk_bf16(v0, v1);
            p.y = pk_bf16(v2, v3);
            bf[t] = __builtin_bit_cast(short4v, p);
        }

        // ---- 31 MFMA layers (input + 30 hidden), bias via C operand, relu+cvt
#pragma unroll
        for (int L = 0; L < NL - 1; ++L) {
            const short4v aF = lA[L * 64 + lane];
            const float4v cB = lB[L * 4 + g];
            float4v d[T];
#pragma unroll
            for (int t = 0; t < T; ++t)
                d[t] = __builtin_amdgcn_mfma_f32_16x16x16bf16_1k(aF, bf[t], cB, 0, 0, 0);
#pragma unroll
            for (int t = 0; t < T; ++t) {
                int2 p;
                p.x = pk_bf16(fmaxf(d[t][0], 0.f), fmaxf(d[t][1], 0.f));
                p.y = pk_bf16(fmaxf(d[t][2], 0.f), fmaxf(d[t][3], 0.f));
                bf[t] = __builtin_bit_cast(short4v, p);
            }
        }

        // ---- output layer: A has W_out only in row 0; y[n] = D[0][n]
        const short4v aO = lA[(NL - 1) * 64 + lane];
        const float4v cO = lB[(NL - 1) * 4 + g];
#pragma unroll
        for (int t = 0; t < T; ++t) {
            float4v d = __builtin_amdgcn_mfma_f32_16x16x16bf16_1k(aO, bf[t], cO, 0, 0, 0);
            if (lane < 16)
                out[(size_t)(tb + t) * 16 + lane] = d[0];
        }
    }
}

extern "C" void kernel_launch(void* const* d_in, const int* in_sizes, int n_in,
                              void* d_out, int out_size, void* d_ws, size_t ws_size,
                              hipStream_t stream) {
    const float* x     = (const float*)d_in[0];
    const float* W_in  = (const float*)d_in[1];
    const float* b_in  = (const float*)d_in[2];
    const float* W_h   = (const float*)d_in[3];
    const float* b_h   = (const float*)d_in[4];
    const float* W_out = (const float*)d_in[5];
    const float* b_out = (const float*)d_in[6];
    float* out = (float*)d_out;

    short4v* wsA = (short4v*)d_ws;
    float*   wsB = (float*)((char*)d_ws + NL * 64 * sizeof(short4v)); // +16384

    prep_kernel<<<NL, 64, 0, stream>>>(W_in, b_in, W_h, b_h, W_out, b_out, wsA, wsB);

    const int tiles  = out_size / 16;                 // 131072
    const int blocks = (tiles + WPB * T - 1) / (WPB * T); // 8192
    mlp_kernel<<<blocks, TPB, 0, stream>>>(x, out, (const float4v*)d_ws, tiles);
}

// Round 2
// 296.303 us; speedup vs baseline: 2.2109x; 2.2109x over previous
//
#include <hip/hip_runtime.h>
#include <stdint.h>

// Batched tiny MLP [B,13]->16->(30x 16->16 relu)->1, fp32 in/out, bf16 MFMA.
// Transposed formulation: mfma_f32_16x16x16_bf16 D layout == B layout, so each
// layer's relu'd output is the next layer's B fragment in-register.
// R2: persistent blocks (1024, fully resident), weights swizzled into LDS once
// per block, x streamed via coalesced dwordx4 -> wave-private LDS staging with
// register prefetch across grid-stride iterations. No barriers in main loop.

typedef __attribute__((ext_vector_type(4))) short short4v;
typedef __attribute__((ext_vector_type(4))) float float4v;

#define S_IN 13
#define H 16
#define NL 32          // mfma layers: 0 = input, 1..30 = hidden, 31 = output
#define TPB 256
#define WPB 4          // waves per block
#define T 4            // 16-sample tiles per wave per iteration
#define NBLOCKS 1024
#define STRIDE (NBLOCKS * WPB * T)   // tiles per grid sweep = 16384

// LDS dword map:
//   [0, 4096)          A-frags: 2 dwords per (L, lane)  (bf16x4)
//   [4096, 4608)       bias[L][m] fp32
//   [4608, 4608+WPB*832) per-wave x staging (4 tiles * 16 samples * 13 dwords)
//   +4 pad dwords (unconditional frag reads may overshoot by 2)
#define XS_BASE 4608
#define LDS_DW (XS_BASE + WPB * 832 + 4)

__device__ __forceinline__ unsigned short bf16_rne(float x) {
    unsigned u = __float_as_uint(x);
    u += 0x7fffu + ((u >> 16) & 1u);
    return (unsigned short)(u >> 16);
}

__device__ __forceinline__ unsigned pk_bf16(float a, float b) {
#if __has_builtin(__builtin_amdgcn_cvt_pk_bf16_f32)
    typedef __attribute__((ext_vector_type(2))) __bf16 bf16x2;
    bf16x2 v = __builtin_amdgcn_cvt_pk_bf16_f32(a, b);
    return __builtin_bit_cast(unsigned, v);
#else
    return (unsigned)bf16_rne(a) | ((unsigned)bf16_rne(b) << 16);
#endif
}

__global__ __launch_bounds__(TPB, 4)
void mlp_kernel(const float* __restrict__ x,
                const float* __restrict__ W_in, const float* __restrict__ b_in,
                const float* __restrict__ W_h,  const float* __restrict__ b_h,
                const float* __restrict__ W_out,const float* __restrict__ b_out,
                float* __restrict__ out, int tiles)
{
    __shared__ unsigned lds[LDS_DW];
    const int tid = threadIdx.x;

    // ---- in-block weight swizzle into MFMA A-fragment layout (once) ----
    for (int s = tid; s < NL * 64; s += TPB) {
        const int L = s >> 6, lane = s & 63, m = lane & 15, gg = lane >> 4;
        float v[4];
#pragma unroll
        for (int i = 0; i < 4; ++i) {
            const int k = 4 * gg + i;
            if (L == 0)       v[i] = (k < S_IN) ? W_in[m * S_IN + k] : 0.f;
            else if (L <= 30) v[i] = W_h[(L - 1) * H * H + m * H + k];
            else              v[i] = (m == 0) ? W_out[k] : 0.f;
        }
        lds[s * 2]     = pk_bf16(v[0], v[1]);
        lds[s * 2 + 1] = pk_bf16(v[2], v[3]);
    }
    for (int s = tid; s < NL * H; s += TPB) {
        const int L = s >> 4, m = s & 15;
        float bv;
        if (L == 0)       bv = b_in[m];
        else if (L <= 30) bv = b_h[(L - 1) * H + m];
        else              bv = (m == 0) ? b_out[0] : 0.f;
        lds[4096 + s] = __float_as_uint(bv);
    }
    __syncthreads();

    const short4v* lA = (const short4v*)lds;            // [NL*64]
    const float4v* lB = (const float4v*)(lds + 4096);   // [NL*4]

    const int lane = tid & 63;
    const int wv   = tid >> 6;
    const int g    = lane >> 4;
    const int col  = lane & 15;
    const int k0   = 4 * g;
    const bool gtop = (k0 == 12);          // k slots 13..15 must be zero
    const int col13 = col * 13;

    unsigned* xs = lds + XS_BASE + wv * 832;   // wave-private staging

    const int wave_id = blockIdx.x * WPB + wv;
    int tb = wave_id * T;

    // prefetch first iteration's x block (4 tiles = 832 dwords, 16B-aligned)
    float4v r0, r1, r2; float r3;
    if (tb < tiles) {
        const float* src = x + (size_t)tb * 208;
        r0 = *(const float4v*)(src + lane * 4);
        r1 = *(const float4v*)(src + 256 + lane * 4);
        r2 = *(const float4v*)(src + 512 + lane * 4);
        r3 = src[768 + lane];
    }

    for (; tb < tiles; tb += STRIDE) {
        // stage current x block (wave-private: no __syncthreads needed)
        *(float4v*)(xs + lane * 4)       = r0;
        *(float4v*)(xs + 256 + lane * 4) = r1;
        *(float4v*)(xs + 512 + lane * 4) = r2;
        xs[768 + lane] = __float_as_uint(r3);

        // issue next iteration's global loads (overlap with compute below)
        const int tbn = tb + STRIDE;
        if (tbn < tiles) {
            const float* src = x + (size_t)tbn * 208;
            r0 = *(const float4v*)(src + lane * 4);
            r1 = *(const float4v*)(src + 256 + lane * 4);
            r2 = *(const float4v*)(src + 512 + lane * 4);
            r3 = src[768 + lane];
        }

        // gather input-layer B fragments from LDS (13-stride: conflict-free)
        short4v bf[T];
#pragma unroll
        for (int t = 0; t < T; ++t) {
            const unsigned* p = xs + t * 208 + col13 + k0;
            float v0 = __uint_as_float(p[0]);
            float v1 = __uint_as_float(p[1]);
            float v2 = __uint_as_float(p[2]);
            float v3 = __uint_as_float(p[3]);
            if (gtop) { v1 = 0.f; v2 = 0.f; v3 = 0.f; }
            int2 pk;
            pk.x = (int)pk_bf16(v0, v1);
            pk.y = (int)pk_bf16(v2, v3);
            bf[t] = __builtin_bit_cast(short4v, pk);
        }

        // 31 layers: bias in C operand, relu + bf16 repack feeds next B frag
#pragma unroll
        for (int L = 0; L < NL - 1; ++L) {
            const short4v aF = lA[L * 64 + lane];
            const float4v cB = lB[L * 4 + g];
            float4v d[T];
#pragma unroll
            for (int t = 0; t < T; ++t)
                d[t] = __builtin_amdgcn_mfma_f32_16x16x16bf16_1k(aF, bf[t], cB, 0, 0, 0);
#pragma unroll
            for (int t = 0; t < T; ++t) {
                int2 pk;
                pk.x = (int)pk_bf16(fmaxf(d[t][0], 0.f), fmaxf(d[t][1], 0.f));
                pk.y = (int)pk_bf16(fmaxf(d[t][2], 0.f), fmaxf(d[t][3], 0.f));
                bf[t] = __builtin_bit_cast(short4v, pk);
            }
        }

        // output layer: W_out lives in row 0 only; y[n] = D[0][n]
        const short4v aO = lA[(NL - 1) * 64 + lane];
        const float4v cO = lB[(NL - 1) * 4 + g];
#pragma unroll
        for (int t = 0; t < T; ++t) {
            float4v d = __builtin_amdgcn_mfma_f32_16x16x16bf16_1k(aO, bf[t], cO, 0, 0, 0);
            if (lane < 16)
                out[(size_t)(tb + t) * 16 + lane] = d[0];
        }
    }
}

extern "C" void kernel_launch(void* const* d_in, const int* in_sizes, int n_in,
                              void* d_out, int out_size, void* d_ws, size_t ws_size,
                              hipStream_t stream) {
    const float* x     = (const float*)d_in[0];
    const float* W_in  = (const float*)d_in[1];
    const float* b_in  = (const float*)d_in[2];
    const float* W_h   = (const float*)d_in[3];
    const float* b_h   = (const float*)d_in[4];
    const float* W_out = (const float*)d_in[5];
    const float* b_out = (const float*)d_in[6];
    float* out = (float*)d_out;

    const int tiles = out_size / 16;                       // 131072
    int blocks = (tiles + WPB * T - 1) / (WPB * T);
    if (blocks > NBLOCKS) blocks = NBLOCKS;
    mlp_kernel<<<blocks, TPB, 0, stream>>>(x, W_in, b_in, W_h, b_h, W_out, b_out,
                                           out, tiles);
}

// Round 3
// 293.797 us; speedup vs baseline: 2.2298x; 1.0085x over previous
//
#include <hip/hip_runtime.h>
#include <stdint.h>

// Batched tiny MLP [B,13]->16->(30x 16->16 relu)->1, fp32 in/out, bf16 MFMA.
// Transposed formulation: mfma_f32_16x16x16_bf16 D layout == B layout, so each
// layer's relu'd output is the next layer's B fragment in-register.
// R3: A-fragments for all 32 layers hoisted into VGPRs (loaded once per wave,
// coalesced dwordx4 + cvt_pk) -- kills the per-layer ds_read_b64 -> MFMA
// latency chain that made R2 latency-bound. Biases in LDS (2 KB), pipelined
// one layer ahead. x staged via coalesced dwordx4 -> wave-private LDS.

typedef __attribute__((ext_vector_type(4))) short short4v;
typedef __attribute__((ext_vector_type(4))) float float4v;

#define S_IN 13
#define H 16
#define NL 32          // mfma layers: 0 = input, 1..30 = hidden, 31 = output
#define TPB 256
#define WPB 4          // waves per block
#define T 4            // 16-sample tiles per wave per iteration
#define NBLOCKS 1024
#define STRIDE (NBLOCKS * WPB * T)   // tiles per grid sweep = 16384

// LDS dword map:
//   [0, 512)                bias[L][m] fp32 (C-operand order by (L, m))
//   [512, 512+WPB*832)      per-wave x staging (4 tiles * 16 samples * 13 dw)
//   +4 pad dwords (frag gather may overshoot by up to 3; zero-initialized)
#define XS_BASE 512
#define LDS_DW (XS_BASE + WPB * 832 + 4)

__device__ __forceinline__ unsigned short bf16_rne(float x) {
    unsigned u = __float_as_uint(x);
    u += 0x7fffu + ((u >> 16) & 1u);
    return (unsigned short)(u >> 16);
}

__device__ __forceinline__ unsigned pk_bf16(float a, float b) {
#if __has_builtin(__builtin_amdgcn_cvt_pk_bf16_f32)
    typedef __attribute__((ext_vector_type(2))) __bf16 bf16x2;
    bf16x2 v = __builtin_amdgcn_cvt_pk_bf16_f32(a, b);
    return __builtin_bit_cast(unsigned, v);
#else
    return (unsigned)bf16_rne(a) | ((unsigned)bf16_rne(b) << 16);
#endif
}

__device__ __forceinline__ short4v pack4(float v0, float v1, float v2, float v3) {
    int2 p;
    p.x = (int)pk_bf16(v0, v1);
    p.y = (int)pk_bf16(v2, v3);
    return __builtin_bit_cast(short4v, p);
}

__global__ __launch_bounds__(TPB, 4)
void mlp_kernel(const float* __restrict__ x,
                const float* __restrict__ W_in, const float* __restrict__ b_in,
                const float* __restrict__ W_h,  const float* __restrict__ b_h,
                const float* __restrict__ W_out,const float* __restrict__ b_out,
                float* __restrict__ out, int tiles)
{
    __shared__ unsigned lds[LDS_DW];
    const int tid = threadIdx.x;

    // ---- stage biases into LDS in C-operand order (once per block) ----
    for (int s = tid; s < NL * H; s += TPB) {
        const int L = s >> 4, m = s & 15;
        float bv;
        if (L == 0)       bv = b_in[m];
        else if (L <= 30) bv = b_h[(L - 1) * H + m];
        else              bv = (m == 0) ? b_out[0] : 0.f;
        lds[s] = __float_as_uint(bv);
    }
    if (tid < 4) lds[XS_BASE + WPB * 832 + tid] = 0;  // zero overshoot pad
    __syncthreads();

    const float4v* lB = (const float4v*)lds;   // [NL*4]

    const int lane = tid & 63;
    const int wv   = tid >> 6;
    const int g    = lane >> 4;
    const int col  = lane & 15;
    const int m    = col;                  // A-fragment row for this lane
    const int k0   = 4 * g;
    const int col13 = col * 13;

    // ---- hoist all 32 layers' A fragments into VGPRs (once per wave) ----
    short4v aF[NL];
    {
        // input layer: W_in[m][k], K padded 13->16 with zeros
        float v0 = W_in[m * S_IN + k0];
        float v1 = (k0 + 1 < S_IN) ? W_in[m * S_IN + k0 + 1] : 0.f;
        float v2 = (k0 + 2 < S_IN) ? W_in[m * S_IN + k0 + 2] : 0.f;
        float v3 = (k0 + 3 < S_IN) ? W_in[m * S_IN + k0 + 3] : 0.f;
        aF[0] = pack4(v0, v1, v2, v3);
    }
#pragma unroll
    for (int L = 1; L <= 30; ++L) {
        // 16B-aligned coalesced dwordx4: 64 lanes cover the full 1KB layer
        float4v w = *(const float4v*)(W_h + (size_t)(L - 1) * 256 + m * 16 + k0);
        aF[L] = pack4(w[0], w[1], w[2], w[3]);
    }
    {
        // output layer: W_out in row 0 only
        float4v w = *(const float4v*)(W_out + k0);
        if (m != 0) { w[0] = 0.f; w[1] = 0.f; w[2] = 0.f; w[3] = 0.f; }
        aF[NL - 1] = pack4(w[0], w[1], w[2], w[3]);
    }

    unsigned* xs = lds + XS_BASE + wv * 832;   // wave-private staging

    const int wave_id = blockIdx.x * WPB + wv;
    int tb = wave_id * T;

    // prefetch first iteration's x block (4 tiles = 832 dwords, 16B-aligned)
    float4v r0, r1, r2; float r3;
    if (tb < tiles) {
        const float* src = x + (size_t)tb * 208;
        r0 = *(const float4v*)(src + lane * 4);
        r1 = *(const float4v*)(src + 256 + lane * 4);
        r2 = *(const float4v*)(src + 512 + lane * 4);
        r3 = src[768 + lane];
    }

    for (; tb < tiles; tb += STRIDE) {
        // stage current x block (wave-private: no __syncthreads needed)
        *(float4v*)(xs + lane * 4)       = r0;
        *(float4v*)(xs + 256 + lane * 4) = r1;
        *(float4v*)(xs + 512 + lane * 4) = r2;
        xs[768 + lane] = __float_as_uint(r3);

        // issue next iteration's global loads (overlap with compute below)
        const int tbn = tb + STRIDE;
        if (tbn < tiles) {
            const float* src = x + (size_t)tbn * 208;
            r0 = *(const float4v*)(src + lane * 4);
            r1 = *(const float4v*)(src + 256 + lane * 4);
            r2 = *(const float4v*)(src + 512 + lane * 4);
            r3 = src[768 + lane];
        }

        // gather input-layer B fragments from LDS (stride 13: conflict-free).
        // k slots 13..15 read neighbor/pad garbage -- finite, and A there is 0.
        short4v bf[T];
#pragma unroll
        for (int t = 0; t < T; ++t) {
            const unsigned* p = xs + t * 208 + col13 + k0;
            bf[t] = pack4(__uint_as_float(p[0]), __uint_as_float(p[1]),
                          __uint_as_float(p[2]), __uint_as_float(p[3]));
        }

        // 31 layers: bias rides in C operand (pipelined one layer ahead),
        // relu + bf16 repack feeds the next layer's B fragment in-register.
        float4v cB = lB[g];                    // layer 0 bias frag
#pragma unroll
        for (int L = 0; L < NL - 1; ++L) {
            const float4v cN = lB[(L + 1) * 4 + g];   // prefetch next bias
            const short4v aL = aF[L];
            float4v d[T];
#pragma unroll
            for (int t = 0; t < T; ++t)
                d[t] = __builtin_amdgcn_mfma_f32_16x16x16bf16_1k(aL, bf[t], cB, 0, 0, 0);
#pragma unroll
            for (int t = 0; t < T; ++t)
                bf[t] = pack4(fmaxf(d[t][0], 0.f), fmaxf(d[t][1], 0.f),
                              fmaxf(d[t][2], 0.f), fmaxf(d[t][3], 0.f));
            cB = cN;
        }

        // output layer: W_out lives in row 0 only; y[n] = D[0][n]
        const short4v aO = aF[NL - 1];
#pragma unroll
        for (int t = 0; t < T; ++t) {
            float4v d = __builtin_amdgcn_mfma_f32_16x16x16bf16_1k(aO, bf[t], cB, 0, 0, 0);
            if (lane < 16)
                out[(size_t)(tb + t) * 16 + lane] = d[0];
        }
    }
}

extern "C" void kernel_launch(void* const* d_in, const int* in_sizes, int n_in,
                              void* d_out, int out_size, void* d_ws, size_t ws_size,
                              hipStream_t stream) {
    const float* x     = (const float*)d_in[0];
    const float* W_in  = (const float*)d_in[1];
    const float* b_in  = (const float*)d_in[2];
    const float* W_h   = (const float*)d_in[3];
    const float* b_h   = (const float*)d_in[4];
    const float* W_out = (const float*)d_in[5];
    const float* b_out = (const float*)d_in[6];
    float* out = (float*)d_out;

    const int tiles = out_size / 16;                       // 131072
    int blocks = (tiles + WPB * T - 1) / (WPB * T);
    if (blocks > NBLOCKS) blocks = NBLOCKS;
    mlp_kernel<<<blocks, TPB, 0, stream>>>(x, W_in, b_in, W_h, b_h, W_out, b_out,
                                           out, tiles);
}